// Round 6
// baseline (86.075 us; speedup 1.0000x reference)
//
#include <hip/hip_runtime.h>

#define NEGV -1.0e12f
constexpr int B = 16, C = 384, Q = 64, D = 2048;
constexpr int IMG = 15360;   // shorts per 64-k B-image (30720 B = 30 1KB-chunks)
constexpr int PITCH = 72;    // shorts per row (144 B, 16B-aligned, uniform banks)
constexpr int NIMG = 32;     // images per batch (D/64)
constexpr int MT = 64;       // c-rows per k_score block
constexpr int KC = 4;        // split-K chunks (512 k each, 8 images)
constexpr int SP = 208;      // S3 partial col pitch

typedef __attribute__((ext_vector_type(8))) short s16x8;
typedef __attribute__((ext_vector_type(4))) float f32x4;
typedef __attribute__((ext_vector_type(4))) unsigned u32x4;

__device__ __forceinline__ unsigned pkbf(float lo, float hi) {
  unsigned ulo = __builtin_bit_cast(unsigned, lo);
  unsigned uhi = __builtin_bit_cast(unsigned, hi);
  return (uhi & 0xFFFF0000u) | (ulo >> 16);
}

// ---------------- kernel 0: merged prep (blocks 0..511) + qstats (512..1535)
__global__ __launch_bounds__(256) void k_pq(
    const float* __restrict__ q, const float* __restrict__ w_cq,
    const float* __restrict__ w_c, const float* __restrict__ w_q,
    const float* __restrict__ W_out, unsigned short* __restrict__ bpk,
    float* __restrict__ qstats) {
  const int t = threadIdx.x;
  if (blockIdx.x < 512) {
    // ---- prep: pack B images. rows [0,64): q*w_cq, [64,128): q*W3c0,
    // [128,192): q*W3c1, 192: w_c, 193: W1c0, 194: W1c1.
    const int s = blockIdx.x & 31, b = blockIdx.x >> 5;
    const int k0 = s * 64;
    unsigned short* img = bpk + ((size_t)b * NIMG + s) * IMG;
#pragma unroll
    for (int i = 0; i < 4; ++i) {
      int idx = t + 256 * i;  // 0..1023
      int qi = idx >> 4, kc = (idx & 15) * 4;
      float4 qv = *(const float4*)(q + ((size_t)b * Q + qi) * D + k0 + kc);
      float4 wq = *(const float4*)(w_cq + k0 + kc);
      const float* wp = W_out + (size_t)(2 * D + k0 + kc) * 2;  // W3 rows
      float4 wa = *(const float4*)(wp);
      float4 wb = *(const float4*)(wp + 4);
      uint2 u;
      u.x = pkbf(qv.x * wq.x, qv.y * wq.y);
      u.y = pkbf(qv.z * wq.z, qv.w * wq.w);
      *(uint2*)(img + qi * PITCH + kc) = u;
      u.x = pkbf(qv.x * wa.x, qv.y * wa.z);
      u.y = pkbf(qv.z * wb.x, qv.w * wb.z);
      *(uint2*)(img + (64 + qi) * PITCH + kc) = u;
      u.x = pkbf(qv.x * wa.y, qv.y * wa.w);
      u.y = pkbf(qv.z * wb.y, qv.w * wb.w);
      *(uint2*)(img + (128 + qi) * PITCH + kc) = u;
    }
    if (t < 48) {  // stats rows 192..194
      int r = t >> 4, kc = (t & 15) * 4;
      uint2 u;
      if (r == 0) {
        float4 w = *(const float4*)(w_c + k0 + kc);
        u.x = pkbf(w.x, w.y);
        u.y = pkbf(w.z, w.w);
      } else {
        const float* wp = W_out + (size_t)(k0 + kc) * 2 + (r - 1);  // W1 col
        u.x = pkbf(wp[0], wp[2]);
        u.y = pkbf(wp[4], wp[6]);
      }
      *(uint2*)(img + (192 + r) * PITCH + kc) = u;
    }
  } else {
    // ---- qstats: per (b,i): q.w_q, q.W2c0, q.W2c1
    int bi = blockIdx.x - 512;
    const float* qrow = q + (size_t)bi * D;
    float a0 = 0.f, a1 = 0.f, a2 = 0.f;
    for (int d = t * 4; d < D; d += 256 * 4) {
      float4 qv = *(const float4*)(qrow + d);
      float4 wq = *(const float4*)(w_q + d);
      const float* wp = W_out + (size_t)(D + d) * 2;
      float4 wa = *(const float4*)(wp);
      float4 wb = *(const float4*)(wp + 4);
      a0 += qv.x * wq.x + qv.y * wq.y + qv.z * wq.z + qv.w * wq.w;
      a1 += qv.x * wa.x + qv.y * wa.z + qv.z * wb.x + qv.w * wb.z;
      a2 += qv.x * wa.y + qv.y * wa.w + qv.z * wb.y + qv.w * wb.w;
    }
    for (int m = 1; m < 64; m <<= 1) {
      a0 += __shfl_xor(a0, m, 64);
      a1 += __shfl_xor(a1, m, 64);
      a2 += __shfl_xor(a2, m, 64);
    }
    __shared__ float red[3][4];
    int w = t >> 6, lane = t & 63;
    if (lane == 0) { red[0][w] = a0; red[1][w] = a1; red[2][w] = a2; }
    __syncthreads();
    if (t == 0) {
      qstats[bi * 3 + 0] = red[0][0] + red[0][1] + red[0][2] + red[0][3];
      qstats[bi * 3 + 1] = red[1][0] + red[1][1] + red[1][2] + red[1][3];
      qstats[bi * 3 + 2] = red[2][0] + red[2][1] + red[2][2] + red[2][3];
    }
  }
}

// ---------------- kernel 1: split-K MFMA score GEMM (no atomics) ------------
// grid (C/MT=6, KC=4, B=16) = 384 blocks, 512 thr (8 waves = 4m x 2n).
__global__ __launch_bounds__(512, 4) void k_score(
    const unsigned short* __restrict__ bpk, const float* __restrict__ c,
    float* __restrict__ S3p) {
  const int t = threadIdx.x;
  const int lane = t & 63, wv = t >> 6;
  const int b = blockIdx.z, kcb = blockIdx.y, r0 = blockIdx.x * MT;
  const int lr = lane & 15, lg = lane >> 4;
  const int mg = wv >> 1, ng = wv & 1;
  const int f0 = ng * 7;
  const int nf = ng ? 6 : 7;

  __shared__ unsigned short sB[2][IMG];

  const float* pA =
      c + ((size_t)b * C + r0 + mg * 16 + lr) * D + kcb * 512 + lg * 8;
  const unsigned short* gB =
      bpk + ((size_t)b * NIMG + kcb * 8) * IMG + lane * 8;

  f32x4 acc[7];
#pragma unroll
  for (int f = 0; f < 7; ++f) acc[f] = f32x4{0.f, 0.f, 0.f, 0.f};

  auto stage = [&](int buf, int s) {
    const unsigned short* g = gB + (size_t)s * IMG;
#pragma unroll
    for (int i = 0; i < 4; ++i) {
      int cid = wv + 8 * i;  // 30 chunks: waves 0..5 do 4, waves 6,7 do 3
      if (cid < 30)
        __builtin_amdgcn_global_load_lds(
            (const __attribute__((address_space(1))) unsigned*)(g + cid * 512),
            (__attribute__((address_space(3))) unsigned*)(&sB[buf][cid * 512]),
            16, 0, 0);
    }
  };
  auto loadA = [&](float4* r, int s) {
    const float* p = pA + s * 64;
    r[0] = *(const float4*)(p);
    r[1] = *(const float4*)(p + 4);
    r[2] = *(const float4*)(p + 32);
    r[3] = *(const float4*)(p + 36);
  };
  auto compute = [&](int buf, const float4* r) {
#pragma unroll
    for (int h = 0; h < 2; ++h) {
      float4 lo = r[2 * h], hi = r[2 * h + 1];
      u32x4 au = {pkbf(lo.x, lo.y), pkbf(lo.z, lo.w), pkbf(hi.x, hi.y),
                  pkbf(hi.z, hi.w)};
      s16x8 af = __builtin_bit_cast(s16x8, au);
#pragma unroll
      for (int f = 0; f < 7; ++f)
        if (f < nf) {
          s16x8 bf = *(const s16x8*)(&sB[buf][((f0 + f) * 16 + lr) * PITCH +
                                              h * 32 + lg * 8]);
          acc[f] =
              __builtin_amdgcn_mfma_f32_16x16x32_bf16(af, bf, acc[f], 0, 0, 0);
        }
    }
  };

  float4 rA[2][4];
  stage(0, 0);
  loadA(rA[0], 0);
#pragma unroll
  for (int s = 0; s < 8; ++s) {
    asm volatile("s_waitcnt vmcnt(4)" ::: "memory");
    __syncthreads();  // publish sB[s&1]; all waves done reading sB[(s+1)&1]
    if (s < 7) {
      stage((s + 1) & 1, s + 1);
      loadA(rA[(s + 1) & 1], s + 1);
    }
    compute(s & 1, rA[s & 1]);
  }

  const size_t rbase = ((size_t)kcb * B + b) * C + r0 + mg * 16 + lg * 4;
#pragma unroll
  for (int f = 0; f < 7; ++f)
    if (f < nf) {
      float* p = S3p + rbase * SP + (f0 + f) * 16 + lr;
#pragma unroll
      for (int j = 0; j < 4; ++j) p[(size_t)j * SP] = acc[f][j];
    }
}

// ---------------- kernel 2: sum partials + row softmax + reductions ---------
__global__ __launch_bounds__(256) void k_soft(
    const float* __restrict__ S3p, const float* __restrict__ qstats,
    const int* __restrict__ c_len, const int* __restrict__ q_len,
    const float* __restrict__ b_c, const float* __restrict__ b_q,
    const float* __restrict__ b_cq, float* __restrict__ mrow,
    float* __restrict__ out12) {
  const int t = threadIdx.x, lane = t & 63;
  const int rg = blockIdx.x * 4 + (t >> 6);  // b*C + r
  const int b = rg / C, r = rg % C;
  float s_cq = 0.f, sc = 0.f, w10 = 0.f, w11 = 0.f, t30 = 0.f, t31 = 0.f;
#pragma unroll
  for (int p = 0; p < KC; ++p) {
    const float* Sr = S3p + ((size_t)p * B * C + rg) * SP;
    s_cq += Sr[lane];
    sc += Sr[192];
    w10 += Sr[193];
    w11 += Sr[194];
    t30 += Sr[64 + lane];
    t31 += Sr[128 + lane];
  }
  const float qs0 = qstats[((b << 6) + lane) * 3 + 0];
  const float qs1 = qstats[((b << 6) + lane) * 3 + 1];
  const float qs2 = qstats[((b << 6) + lane) * 3 + 2];
  float s = s_cq + sc + qs0 + b_c[0] + b_q[0] + b_cq[0];
  const int cl = c_len[b], ql = q_len[b];
  bool masked = (lane >= ql) || ((r >= cl) && (lane < Q - 1));
  if (masked) s += NEGV;
  float mx = s;
  for (int m = 1; m < 64; m <<= 1) mx = fmaxf(mx, __shfl_xor(mx, m, 64));
  float e = __expf(s - mx);
  float den = e;
  for (int m = 1; m < 64; m <<= 1) den += __shfl_xor(den, m, 64);
  float a = e / den;
  float v0 = a * (qs1 + t30);
  float v1 = a * (qs2 + t31);
  for (int m = 1; m < 64; m <<= 1) {
    v0 += __shfl_xor(v0, m, 64);
    v1 += __shfl_xor(v1, m, 64);
  }
  if (lane == 0) {
    mrow[rg] = mx;
    out12[rg * 2 + 0] = w10 + v0;
    out12[rg * 2 + 1] = w11 + v1;
  }
}

// ---------------- kernel 3: fused q2c + term4 (single pass over c) ----------
// grid (32 d-chunks, B), 512 thr. LDS-caches c[b,:,chunk]; pass A builds
// q2c partial for the chunk (batt recomputed per block); pass B row-dots.
__global__ __launch_bounds__(512) void k_fused(
    const float* __restrict__ c, const float* __restrict__ mrow,
    const float* __restrict__ W_out, float* __restrict__ partial) {
  const int ch = blockIdx.x, b = blockIdx.y;
  const int d0 = ch * 64;
  const int t = threadIdx.x, lane = t & 63, wv = t >> 6;
  __shared__ float c_sh[384 * 68];  // pitch 68: 2-way banks only
  __shared__ float red[32 * 68];
  __shared__ float batt[C];
  __shared__ float rmx[8], rsm[8];

  // batt = softmax over mrow[b,:]
  float m = (t < C) ? mrow[b * C + t] : -3.0e38f;
  float mx = m;
  for (int o = 1; o < 64; o <<= 1) mx = fmaxf(mx, __shfl_xor(mx, o, 64));
  if (lane == 0) rmx[wv] = mx;
  __syncthreads();
  mx = rmx[0];
#pragma unroll
  for (int i = 1; i < 8; ++i) mx = fmaxf(mx, rmx[i]);
  float e = (t < C) ? __expf(m - mx) : 0.f;
  float sm = e;
  for (int o = 1; o < 64; o <<= 1) sm += __shfl_xor(sm, o, 64);
  if (lane == 0) rsm[wv] = sm;
  __syncthreads();
  sm = rsm[0] + rsm[1] + rsm[2] + rsm[3] + rsm[4] + rsm[5] + rsm[6] + rsm[7];
  if (t < C) batt[t] = e / sm;
  __syncthreads();

  // pass A: stream c chunk -> LDS, accumulate q2c partials
  const int colq = t & 15, rsub = t >> 4;
  const float* cb = c + ((size_t)b * C + rsub) * D + d0 + colq * 4;
  float4 a4 = {0.f, 0.f, 0.f, 0.f};
#pragma unroll
  for (int it = 0; it < 12; ++it) {
    int r = rsub + 32 * it;
    float4 v = *(const float4*)(cb + (size_t)32 * it * D);
    *(float4*)&c_sh[r * 68 + colq * 4] = v;
    float w = batt[r];
    a4.x += w * v.x; a4.y += w * v.y; a4.z += w * v.z; a4.w += w * v.w;
  }
  *(float4*)&red[rsub * 68 + colq * 4] = a4;
  __syncthreads();

  // finalize per-lane d: s = q2c[d] * W4[d, col]
  float q2 = 0.f;
#pragma unroll
  for (int g = 0; g < 32; ++g) q2 += red[g * 68 + lane];
  float2 w4 = *(const float2*)(W_out + (size_t)(3 * D + d0 + lane) * 2);
  float s0 = q2 * w4.x, s1 = q2 * w4.y;

  // pass B: per-row dot over the 64 cached d
  float* po = partial + ((size_t)ch * B + b) * C * 2;
  for (int i = 0; i < 48; ++i) {
    int r = wv * 48 + i;
    float v = c_sh[r * 68 + lane];
    float v0 = v * s0, v1 = v * s1;
    for (int o = 1; o < 64; o <<= 1) {
      v0 += __shfl_xor(v0, o, 64);
      v1 += __shfl_xor(v1, o, 64);
    }
    if (lane == 0) { po[r * 2] = v0; po[r * 2 + 1] = v1; }
  }
}

// ---------------- kernel 4: sum chunk partials + bias + mask + write --------
__global__ __launch_bounds__(256) void k_fin(
    const float* __restrict__ partial, const float* __restrict__ out12,
    const float* __restrict__ b_out, const int* __restrict__ c_len,
    float* __restrict__ outp) {
  const int idx = blockIdx.x * 256 + threadIdx.x;  // b*C + r
  const int b = idx / C, r = idx % C;
  float o0 = out12[idx * 2 + 0], o1 = out12[idx * 2 + 1];
#pragma unroll
  for (int ch = 0; ch < 32; ++ch) {
    const float* p = partial + (((size_t)ch * B + b) * C + r) * 2;
    o0 += p[0];
    o1 += p[1];
  }
  o0 += b_out[0];
  o1 += b_out[1];
  if (r >= c_len[b] && r < C - 1) { o0 = NEGV; o1 = NEGV; }
  outp[idx] = o0;
  outp[B * C + idx] = o1;
}

extern "C" void kernel_launch(void* const* d_in, const int* in_sizes, int n_in,
                              void* d_out, int out_size, void* d_ws,
                              size_t ws_size, hipStream_t stream) {
  const float* c = (const float*)d_in[0];
  const float* q = (const float*)d_in[1];
  const int* c_len = (const int*)d_in[2];
  const int* q_len = (const int*)d_in[3];
  const float* w_c = (const float*)d_in[4];
  const float* b_c = (const float*)d_in[5];
  const float* w_q = (const float*)d_in[6];
  const float* b_q = (const float*)d_in[7];
  const float* w_cq = (const float*)d_in[8];
  const float* b_cq = (const float*)d_in[9];
  const float* W_out = (const float*)d_in[10];
  const float* b_out = (const float*)d_in[11];
  float* outp = (float*)d_out;

  // ws: bpk (15.73 MB) | S3 partials (20.45 MB) | smalls | term4 partials
  unsigned short* bpk = (unsigned short*)d_ws;
  const size_t bpk_bytes = (size_t)B * NIMG * IMG * 2;  // 15,728,640
  float* S3p = (float*)((char*)d_ws + bpk_bytes);
  const size_t s3_elems = (size_t)KC * B * C * SP;      // 5,111,808
  float* ws = S3p + s3_elems;
  float* qstats = ws;                     // B*Q*3  = 3072
  float* mrow = ws + 3072;                // B*C    = 6144
  float* out12 = ws + 3072 + 6144;        // B*C*2  = 12288
  float* partial = ws + 3072 + 6144 + 12288;  // 32*B*C*2 = 393216

  hipLaunchKernelGGL(k_pq, dim3(512 + B * Q), dim3(256), 0, stream, q, w_cq,
                     w_c, w_q, W_out, bpk, qstats);
  hipLaunchKernelGGL(k_score, dim3(C / MT, KC, B), dim3(512), 0, stream, bpk,
                     c, S3p);
  hipLaunchKernelGGL(k_soft, dim3(B * C / 4), dim3(256), 0, stream, S3p,
                     qstats, c_len, q_len, b_c, b_q, b_cq, mrow, out12);
  hipLaunchKernelGGL(k_fused, dim3(32, B), dim3(512), 0, stream, c, mrow,
                     W_out, partial);
  hipLaunchKernelGGL(k_fin, dim3(B * C / 256), dim3(256), 0, stream, partial,
                     out12, b_out, c_len, outp);
}

// Round 7
// 63.748 us; speedup vs baseline: 1.3502x; 1.3502x over previous
//
#include <hip/hip_runtime.h>

#define NEGV -1.0e12f
constexpr int B = 16, C = 384, Q = 64, D = 2048;
constexpr int IMG = 15360;   // shorts per 64-k B-image (30720 B = 30 1KB-chunks)
constexpr int PITCH = 72;    // shorts per row (144 B, 16B-aligned, uniform banks)
constexpr int NIMG = 32;     // images per batch (D/64)
constexpr int MT = 64;       // c-rows per k_score block
constexpr int KC = 4;        // split-K chunks (512 k each, 8 images)
constexpr int SP = 208;      // S3 partial col pitch

typedef __attribute__((ext_vector_type(8))) short s16x8;
typedef __attribute__((ext_vector_type(4))) float f32x4;
typedef __attribute__((ext_vector_type(4))) unsigned u32x4;

__device__ __forceinline__ unsigned pkbf(float lo, float hi) {
  unsigned ulo = __builtin_bit_cast(unsigned, lo);
  unsigned uhi = __builtin_bit_cast(unsigned, hi);
  return (uhi & 0xFFFF0000u) | (ulo >> 16);
}

// ---------------- kernel 0: merged prep (blocks 0..511) + qstats (512..1535)
__global__ __launch_bounds__(256) void k_pq(
    const float* __restrict__ q, const float* __restrict__ w_cq,
    const float* __restrict__ w_c, const float* __restrict__ w_q,
    const float* __restrict__ W_out, unsigned short* __restrict__ bpk,
    float* __restrict__ qstats) {
  const int t = threadIdx.x;
  if (blockIdx.x < 512) {
    const int s = blockIdx.x & 31, b = blockIdx.x >> 5;
    const int k0 = s * 64;
    unsigned short* img = bpk + ((size_t)b * NIMG + s) * IMG;
#pragma unroll
    for (int i = 0; i < 4; ++i) {
      int idx = t + 256 * i;  // 0..1023
      int qi = idx >> 4, kc = (idx & 15) * 4;
      float4 qv = *(const float4*)(q + ((size_t)b * Q + qi) * D + k0 + kc);
      float4 wq = *(const float4*)(w_cq + k0 + kc);
      const float* wp = W_out + (size_t)(2 * D + k0 + kc) * 2;  // W3 rows
      float4 wa = *(const float4*)(wp);
      float4 wb = *(const float4*)(wp + 4);
      uint2 u;
      u.x = pkbf(qv.x * wq.x, qv.y * wq.y);
      u.y = pkbf(qv.z * wq.z, qv.w * wq.w);
      *(uint2*)(img + qi * PITCH + kc) = u;
      u.x = pkbf(qv.x * wa.x, qv.y * wa.z);
      u.y = pkbf(qv.z * wb.x, qv.w * wb.z);
      *(uint2*)(img + (64 + qi) * PITCH + kc) = u;
      u.x = pkbf(qv.x * wa.y, qv.y * wa.w);
      u.y = pkbf(qv.z * wb.y, qv.w * wb.w);
      *(uint2*)(img + (128 + qi) * PITCH + kc) = u;
    }
    if (t < 48) {  // stats rows 192..194
      int r = t >> 4, kc = (t & 15) * 4;
      uint2 u;
      if (r == 0) {
        float4 w = *(const float4*)(w_c + k0 + kc);
        u.x = pkbf(w.x, w.y);
        u.y = pkbf(w.z, w.w);
      } else {
        const float* wp = W_out + (size_t)(k0 + kc) * 2 + (r - 1);  // W1 col
        u.x = pkbf(wp[0], wp[2]);
        u.y = pkbf(wp[4], wp[6]);
      }
      *(uint2*)(img + (192 + r) * PITCH + kc) = u;
    }
  } else {
    int bi = blockIdx.x - 512;
    const float* qrow = q + (size_t)bi * D;
    float a0 = 0.f, a1 = 0.f, a2 = 0.f;
    for (int d = t * 4; d < D; d += 256 * 4) {
      float4 qv = *(const float4*)(qrow + d);
      float4 wq = *(const float4*)(w_q + d);
      const float* wp = W_out + (size_t)(D + d) * 2;
      float4 wa = *(const float4*)(wp);
      float4 wb = *(const float4*)(wp + 4);
      a0 += qv.x * wq.x + qv.y * wq.y + qv.z * wq.z + qv.w * wq.w;
      a1 += qv.x * wa.x + qv.y * wa.z + qv.z * wb.x + qv.w * wb.z;
      a2 += qv.x * wa.y + qv.y * wa.w + qv.z * wb.y + qv.w * wb.w;
    }
    for (int m = 1; m < 64; m <<= 1) {
      a0 += __shfl_xor(a0, m, 64);
      a1 += __shfl_xor(a1, m, 64);
      a2 += __shfl_xor(a2, m, 64);
    }
    __shared__ float red[3][4];
    int w = t >> 6, lane = t & 63;
    if (lane == 0) { red[0][w] = a0; red[1][w] = a1; red[2][w] = a2; }
    __syncthreads();
    if (t == 0) {
      qstats[bi * 3 + 0] = red[0][0] + red[0][1] + red[0][2] + red[0][3];
      qstats[bi * 3 + 1] = red[1][0] + red[1][1] + red[1][2] + red[1][3];
      qstats[bi * 3 + 2] = red[2][0] + red[2][1] + red[2][2] + red[2][3];
    }
  }
}

// ---------------- kernel 1: split-K MFMA score GEMM (no atomics) ------------
// grid (C/MT=6, KC=4, B=16) = 384 blocks, 512 thr (8 waves = 4m x 2n).
__global__ __launch_bounds__(512, 4) void k_score(
    const unsigned short* __restrict__ bpk, const float* __restrict__ c,
    float* __restrict__ S3p) {
  const int t = threadIdx.x;
  const int lane = t & 63, wv = t >> 6;
  const int b = blockIdx.z, kcb = blockIdx.y, r0 = blockIdx.x * MT;
  const int lr = lane & 15, lg = lane >> 4;
  const int mg = wv >> 1, ng = wv & 1;
  const int f0 = ng * 7;
  const int nf = ng ? 6 : 7;

  __shared__ unsigned short sB[2][IMG];

  const float* pA =
      c + ((size_t)b * C + r0 + mg * 16 + lr) * D + kcb * 512 + lg * 8;
  const unsigned short* gB =
      bpk + ((size_t)b * NIMG + kcb * 8) * IMG + lane * 8;

  f32x4 acc[7];
#pragma unroll
  for (int f = 0; f < 7; ++f) acc[f] = f32x4{0.f, 0.f, 0.f, 0.f};

  auto stage = [&](int buf, int s) {
    const unsigned short* g = gB + (size_t)s * IMG;
#pragma unroll
    for (int i = 0; i < 4; ++i) {
      int cid = wv + 8 * i;  // 30 chunks: waves 0..5 do 4, waves 6,7 do 3
      if (cid < 30)
        __builtin_amdgcn_global_load_lds(
            (const __attribute__((address_space(1))) unsigned*)(g + cid * 512),
            (__attribute__((address_space(3))) unsigned*)(&sB[buf][cid * 512]),
            16, 0, 0);
    }
  };
  auto loadA = [&](float4* r, int s) {
    const float* p = pA + s * 64;
    r[0] = *(const float4*)(p);
    r[1] = *(const float4*)(p + 4);
    r[2] = *(const float4*)(p + 32);
    r[3] = *(const float4*)(p + 36);
  };
  auto compute = [&](int buf, const float4* r) {
#pragma unroll
    for (int h = 0; h < 2; ++h) {
      float4 lo = r[2 * h], hi = r[2 * h + 1];
      u32x4 au = {pkbf(lo.x, lo.y), pkbf(lo.z, lo.w), pkbf(hi.x, hi.y),
                  pkbf(hi.z, hi.w)};
      s16x8 af = __builtin_bit_cast(s16x8, au);
#pragma unroll
      for (int f = 0; f < 7; ++f)
        if (f < nf) {
          s16x8 bf = *(const s16x8*)(&sB[buf][((f0 + f) * 16 + lr) * PITCH +
                                              h * 32 + lg * 8]);
          acc[f] =
              __builtin_amdgcn_mfma_f32_16x16x32_bf16(af, bf, acc[f], 0, 0, 0);
        }
    }
  };

  float4 rA[2][4];
  stage(0, 0);
  loadA(rA[0], 0);
#pragma unroll
  for (int s = 0; s < 8; ++s) {
    asm volatile("s_waitcnt vmcnt(4)" ::: "memory");
    __syncthreads();  // publish sB[s&1]; all waves done reading sB[(s+1)&1]
    if (s < 7) {
      stage((s + 1) & 1, s + 1);
      loadA(rA[(s + 1) & 1], s + 1);
    }
    compute(s & 1, rA[s & 1]);
  }

  const size_t rbase = ((size_t)kcb * B + b) * C + r0 + mg * 16 + lg * 4;
#pragma unroll
  for (int f = 0; f < 7; ++f)
    if (f < nf) {
      float* p = S3p + rbase * SP + (f0 + f) * 16 + lr;
#pragma unroll
      for (int j = 0; j < 4; ++j) p[(size_t)j * SP] = acc[f][j];
    }
}

// ---------------- kernel 2: sum partials + row softmax + reductions ---------
__global__ __launch_bounds__(256) void k_soft(
    const float* __restrict__ S3p, const float* __restrict__ qstats,
    const int* __restrict__ c_len, const int* __restrict__ q_len,
    const float* __restrict__ b_c, const float* __restrict__ b_q,
    const float* __restrict__ b_cq, float* __restrict__ mrow,
    float* __restrict__ out12) {
  const int t = threadIdx.x, lane = t & 63;
  const int rg = blockIdx.x * 4 + (t >> 6);  // b*C + r
  const int b = rg / C, r = rg % C;
  float s_cq = 0.f, sc = 0.f, w10 = 0.f, w11 = 0.f, t30 = 0.f, t31 = 0.f;
#pragma unroll
  for (int p = 0; p < KC; ++p) {
    const float* Sr = S3p + ((size_t)p * B * C + rg) * SP;
    s_cq += Sr[lane];
    sc += Sr[192];
    w10 += Sr[193];
    w11 += Sr[194];
    t30 += Sr[64 + lane];
    t31 += Sr[128 + lane];
  }
  const float qs0 = qstats[((b << 6) + lane) * 3 + 0];
  const float qs1 = qstats[((b << 6) + lane) * 3 + 1];
  const float qs2 = qstats[((b << 6) + lane) * 3 + 2];
  float s = s_cq + sc + qs0 + b_c[0] + b_q[0] + b_cq[0];
  const int cl = c_len[b], ql = q_len[b];
  bool masked = (lane >= ql) || ((r >= cl) && (lane < Q - 1));
  if (masked) s += NEGV;
  float mx = s;
  for (int m = 1; m < 64; m <<= 1) mx = fmaxf(mx, __shfl_xor(mx, m, 64));
  float e = __expf(s - mx);
  float den = e;
  for (int m = 1; m < 64; m <<= 1) den += __shfl_xor(den, m, 64);
  float a = e / den;
  float v0 = a * (qs1 + t30);
  float v1 = a * (qs2 + t31);
  for (int m = 1; m < 64; m <<= 1) {
    v0 += __shfl_xor(v0, m, 64);
    v1 += __shfl_xor(v1, m, 64);
  }
  if (lane == 0) {
    mrow[rg] = mx;
    out12[rg * 2 + 0] = w10 + v0;
    out12[rg * 2 + 1] = w11 + v1;
  }
}

// ---------------- kernel 3: q2c GEMV fused with W4 -> u vectors -------------
// grid (32 d-chunks of 64, B), 256 thr. u[d,0:2] = q2c[d] * W4[d,0:2].
__global__ __launch_bounds__(256) void k_q2cu(
    const float* __restrict__ c, const float* __restrict__ mrow,
    const float* __restrict__ W_out, float* __restrict__ uvec) {
  const int ch = blockIdx.x, b = blockIdx.y;
  const int t = threadIdx.x, lane = t & 63, wv = t >> 6;
  __shared__ float batt[C];
  __shared__ float rmx[4], rsm[4];
  __shared__ float redq[4][64];

  // batt = softmax over mrow[b,:]
  float m1 = mrow[b * C + t];
  float m2 = (t < C - 256) ? mrow[b * C + 256 + t] : -3.0e38f;
  float mx = fmaxf(m1, m2);
  for (int o = 1; o < 64; o <<= 1) mx = fmaxf(mx, __shfl_xor(mx, o, 64));
  if (lane == 0) rmx[wv] = mx;
  __syncthreads();
  mx = fmaxf(fmaxf(rmx[0], rmx[1]), fmaxf(rmx[2], rmx[3]));
  float e1 = __expf(m1 - mx);
  float e2 = (t < C - 256) ? __expf(m2 - mx) : 0.f;
  float sum = e1 + e2;
  for (int o = 1; o < 64; o <<= 1) sum += __shfl_xor(sum, o, 64);
  if (lane == 0) rsm[wv] = sum;
  __syncthreads();
  sum = rsm[0] + rsm[1] + rsm[2] + rsm[3];
  batt[t] = e1 / sum;
  if (t < C - 256) batt[256 + t] = e2 / sum;
  __syncthreads();

  // q2c partial: thread owns d = ch*64 + lane, row-group rg = wv (8 rows/iter)
  const int d = ch * 64 + lane;
  const float* p = c + ((size_t)b * C + wv * 8) * D + d;
  float a[8] = {0.f, 0.f, 0.f, 0.f, 0.f, 0.f, 0.f, 0.f};
  for (int r0 = 0; r0 < 384; r0 += 32) {
    const float* pr = p + (size_t)r0 * D;
    const float* bt = &batt[r0 + wv * 8];
#pragma unroll
    for (int j = 0; j < 8; ++j) a[j] += bt[j] * pr[(size_t)j * D];
  }
  float acc = ((a[0] + a[1]) + (a[2] + a[3])) + ((a[4] + a[5]) + (a[6] + a[7]));
  redq[wv][lane] = acc;
  __syncthreads();
  if (t < 64) {
    float s = redq[0][t] + redq[1][t] + redq[2][t] + redq[3][t];
    int dd = ch * 64 + t;
    float2 w4 = *(const float2*)(W_out + (size_t)(3 * D + dd) * 2);
    float2 u = {s * w4.x, s * w4.y};
    *(float2*)(uvec + ((size_t)b * D + dd) * 2) = u;
  }
}

// ---------------- kernel 4: term4 row-dots + bias + mask + final write ------
// grid (C/8=48, B), 512 thr (8 waves), wave per row; u staged in LDS.
__global__ __launch_bounds__(512) void k_out(
    const float* __restrict__ c, const float* __restrict__ uvec,
    const float* __restrict__ out12, const float* __restrict__ b_out,
    const int* __restrict__ c_len, float* __restrict__ outp) {
  const int b = blockIdx.y, r0 = blockIdx.x * 8;
  const int t = threadIdx.x, lane = t & 63, wv = t >> 6;
  __shared__ float u_sh[2 * D];  // interleaved {u0,u1} pairs

  // stage u: 512 thr x 8 floats = 4096
  {
    const float* src = uvec + (size_t)b * D * 2 + t * 8;
    float4 v0 = *(const float4*)(src);
    float4 v1 = *(const float4*)(src + 4);
    *(float4*)&u_sh[t * 8] = v0;
    *(float4*)&u_sh[t * 8 + 4] = v1;
  }
  __syncthreads();

  const int r = r0 + wv;
  const float* crow = c + ((size_t)b * C + r) * D + lane * 4;
  float o0 = 0.f, o1 = 0.f;
#pragma unroll
  for (int it = 0; it < 8; ++it) {
    float4 v = *(const float4*)(crow + it * 256);
    const float* us = &u_sh[(lane * 4 + it * 256) * 2];
    float4 ua = *(const float4*)(us);
    float4 ub = *(const float4*)(us + 4);
    o0 += v.x * ua.x + v.y * ua.z + v.z * ub.x + v.w * ub.z;
    o1 += v.x * ua.y + v.y * ua.w + v.z * ub.y + v.w * ub.w;
  }
  for (int o = 1; o < 64; o <<= 1) {
    o0 += __shfl_xor(o0, o, 64);
    o1 += __shfl_xor(o1, o, 64);
  }
  if (lane == 0) {
    const int idx = b * C + r;
    o0 += out12[idx * 2 + 0] + b_out[0];
    o1 += out12[idx * 2 + 1] + b_out[1];
    if (r >= c_len[b] && r < C - 1) { o0 = NEGV; o1 = NEGV; }
    outp[idx] = o0;
    outp[B * C + idx] = o1;
  }
}

extern "C" void kernel_launch(void* const* d_in, const int* in_sizes, int n_in,
                              void* d_out, int out_size, void* d_ws,
                              size_t ws_size, hipStream_t stream) {
  const float* c = (const float*)d_in[0];
  const float* q = (const float*)d_in[1];
  const int* c_len = (const int*)d_in[2];
  const int* q_len = (const int*)d_in[3];
  const float* w_c = (const float*)d_in[4];
  const float* b_c = (const float*)d_in[5];
  const float* w_q = (const float*)d_in[6];
  const float* b_q = (const float*)d_in[7];
  const float* w_cq = (const float*)d_in[8];
  const float* b_cq = (const float*)d_in[9];
  const float* W_out = (const float*)d_in[10];
  const float* b_out = (const float*)d_in[11];
  float* outp = (float*)d_out;

  // ws: bpk (15.73 MB) | S3 partials (20.45 MB) | smalls | uvec
  unsigned short* bpk = (unsigned short*)d_ws;
  const size_t bpk_bytes = (size_t)B * NIMG * IMG * 2;  // 15,728,640
  float* S3p = (float*)((char*)d_ws + bpk_bytes);
  const size_t s3_elems = (size_t)KC * B * C * SP;      // 5,111,808
  float* ws = S3p + s3_elems;
  float* qstats = ws;                     // B*Q*3  = 3072
  float* mrow = ws + 3072;                // B*C    = 6144
  float* out12 = ws + 3072 + 6144;        // B*C*2  = 12288
  float* uvec = ws + 3072 + 6144 + 12288; // B*D*2  = 65536

  hipLaunchKernelGGL(k_pq, dim3(512 + B * Q), dim3(256), 0, stream, q, w_cq,
                     w_c, w_q, W_out, bpk, qstats);
  hipLaunchKernelGGL(k_score, dim3(C / MT, KC, B), dim3(512), 0, stream, bpk,
                     c, S3p);
  hipLaunchKernelGGL(k_soft, dim3(B * C / 4), dim3(256), 0, stream, S3p,
                     qstats, c_len, q_len, b_c, b_q, b_cq, mrow, out12);
  hipLaunchKernelGGL(k_q2cu, dim3(32, B), dim3(256), 0, stream, c, mrow,
                     W_out, uvec);
  hipLaunchKernelGGL(k_out, dim3(C / 8, B), dim3(512), 0, stream, c, uvec,
                     out12, b_out, c_len, outp);
}